// Round 1
// baseline (639.308 us; speedup 1.0000x reference)
//
#include <hip/hip_runtime.h>

#define NT 1024
#define RPT 8
#define NITER 200

__device__ __forceinline__ float wsum(float v) {
  v += __shfl_xor(v, 1);
  v += __shfl_xor(v, 2);
  v += __shfl_xor(v, 4);
  v += __shfl_xor(v, 8);
  v += __shfl_xor(v, 16);
  v += __shfl_xor(v, 32);
  return v;
}

// Sinkhorn in scale-invariant multiplicative form.
// e_ij tracks exp(K_ij + g_j) up to arbitrary per-row / per-column scales.
// P = e * w * b / c is exactly invariant to those scales.
__global__ __launch_bounds__(NT, 4) void sinkhorn_k(
    const float* __restrict__ theta,
    const float* __restrict__ phi,
    const float* __restrict__ sens_raw,
    const float* __restrict__ n_raw,
    float* __restrict__ out)
{
  constexpr float S1C = 72.13475204444817f;      // (1/EPS) * log2(e) = 50*log2(e)
  constexpr float L2E = 1.4426950408889634f;
  constexpr float ERR0 = 6.25e-2f;               // 2^-4   (bits=2)
  constexpr float ERR1 = 1.5625e-2f;             // 2^-6   (bits=3)
  constexpr float ERR2 = 3.90625e-3f;            // 2^-8   (bits=4)
  constexpr float ERR3 = 9.765625e-4f;           // 2^-10  (bits=5)
  constexpr float ERR4 = 2.44140625e-4f;         // 2^-12  (bits=6)
  constexpr float ERR5 = 1.52587890625e-5f;      // 2^-16  (bits=8)
  constexpr float ERR6 = 9.5367431640625e-7f;    // 2^-20  (bits=10)
  constexpr float ERR7 = 5.9604644775390625e-8f; // 2^-24  (bits=12)

  const int tid  = threadIdx.x;
  const int lane = tid & 63;
  const int wave = tid >> 6;

  __shared__ float part[NT];
  __shared__ __align__(16) float rbuf[8];
  __shared__ __align__(16) float g2buf[8];
  __shared__ float sums[2];
  __shared__ float stot;

  if (tid == 0) {
    sums[0] = 0.f; sums[1] = 0.f; stot = 0.f;
    #pragma unroll
    for (int j = 0; j < 8; ++j) g2buf[j] = 0.f;
  }
  __syncthreads();

  // ---- init: per-row loads and global sums over n, sens_raw ----
  float nv[RPT], sv[RPT];
  float pn = 0.f, ps = 0.f;
  #pragma unroll
  for (int k = 0; k < RPT; ++k) {
    int rr = tid + NT * k;
    nv[k] = fmaf(n_raw[rr], 1e5f, 1e3f);
    sv[k] = sens_raw[rr];
    pn += nv[k];
    ps += sv[k];
  }
  pn = wsum(pn);
  ps = wsum(ps);
  if (lane == 0) { atomicAdd(&sums[0], pn); atomicAdd(&sums[1], ps); }
  __syncthreads();
  const float inv_sumn = __builtin_amdgcn_rcpf(sums[0]);
  const float inv_ss   = __builtin_amdgcn_rcpf(sums[1] + 1e-12f);

  float a_i[RPT], rowc[RPT];
  #pragma unroll
  for (int k = 0; k < RPT; ++k) {
    a_i[k]  = nv[k] * inv_sumn;                 // row marginal a_i
    rowc[k] = nv[k] * (sv[k] * inv_ss) * S1C;   // S1C * n_i * sens_i
  }

  // ---- b = softmax(phi); threads (lane&7)==0 of wave 0 own column j=lane>>3 ----
  float ph[8];
  #pragma unroll
  for (int j = 0; j < 8; ++j) ph[j] = phi[j];
  float pmx = ph[0];
  #pragma unroll
  for (int j = 1; j < 8; ++j) pmx = fmaxf(pmx, ph[j]);
  float bv[8];
  float bs = 0.f;
  #pragma unroll
  for (int j = 0; j < 8; ++j) { bv[j] = __builtin_amdgcn_exp2f((ph[j] - pmx) * L2E); bs += bv[j]; }
  const float ibs = __builtin_amdgcn_rcpf(bs);
  float myb = 0.f, myl2b = 0.f, g2 = 0.f;
  #pragma unroll
  for (int j = 0; j < 8; ++j) {
    float b = bv[j] * ibs;
    if (wave == 0 && (lane & 7) == 0 && (lane >> 3) == j) {
      myb   = b;
      myl2b = __builtin_amdgcn_logf(b);  // log2(b)
    }
  }

  float e[RPT][8];
  float w[RPT];
  float r[8];

  #pragma unroll 1
  for (int t = 0; t < NITER; ++t) {
    // ---- periodic refresh: rebuild e = 2^(K2 + g2 - rowmax) from theta ----
    if ((t & 15) == 0) {
      float g2r[8];
      {
        float4 ga = *reinterpret_cast<const float4*>(&g2buf[0]);
        float4 gb = *reinterpret_cast<const float4*>(&g2buf[4]);
        g2r[0] = ga.x; g2r[1] = ga.y; g2r[2] = ga.z; g2r[3] = ga.w;
        g2r[4] = gb.x; g2r[5] = gb.y; g2r[6] = gb.z; g2r[7] = gb.w;
      }
      #pragma unroll
      for (int k = 0; k < RPT; ++k) {
        const float4* tp = reinterpret_cast<const float4*>(theta + (size_t)(tid + NT * k) * 8);
        float4 t0 = tp[0];
        float4 t1 = tp[1];
        float x0 = fmaf(t0.x, S1C, fmaf(-rowc[k], ERR0, g2r[0]));
        float x1 = fmaf(t0.y, S1C, fmaf(-rowc[k], ERR1, g2r[1]));
        float x2 = fmaf(t0.z, S1C, fmaf(-rowc[k], ERR2, g2r[2]));
        float x3 = fmaf(t0.w, S1C, fmaf(-rowc[k], ERR3, g2r[3]));
        float x4 = fmaf(t1.x, S1C, fmaf(-rowc[k], ERR4, g2r[4]));
        float x5 = fmaf(t1.y, S1C, fmaf(-rowc[k], ERR5, g2r[5]));
        float x6 = fmaf(t1.z, S1C, fmaf(-rowc[k], ERR6, g2r[6]));
        float x7 = fmaf(t1.w, S1C, fmaf(-rowc[k], ERR7, g2r[7]));
        float mx = fmaxf(fmaxf(fmaxf(x0, x1), fmaxf(x2, x3)),
                         fmaxf(fmaxf(x4, x5), fmaxf(x6, x7)));
        e[k][0] = __builtin_amdgcn_exp2f(x0 - mx);
        e[k][1] = __builtin_amdgcn_exp2f(x1 - mx);
        e[k][2] = __builtin_amdgcn_exp2f(x2 - mx);
        e[k][3] = __builtin_amdgcn_exp2f(x3 - mx);
        e[k][4] = __builtin_amdgcn_exp2f(x4 - mx);
        e[k][5] = __builtin_amdgcn_exp2f(x5 - mx);
        e[k][6] = __builtin_amdgcn_exp2f(x6 - mx);
        e[k][7] = __builtin_amdgcn_exp2f(x7 - mx);
      }
    }

    // ---- row phase: S, max, w, column partials; renormalize e rows ----
    float cc[8];
    #pragma unroll
    for (int j = 0; j < 8; ++j) cc[j] = 0.f;
    #pragma unroll
    for (int k = 0; k < RPT; ++k) {
      float s01 = e[k][0] + e[k][1];
      float s23 = e[k][2] + e[k][3];
      float s45 = e[k][4] + e[k][5];
      float s67 = e[k][6] + e[k][7];
      float S   = (s01 + s23) + (s45 + s67);
      float m01 = fmaxf(e[k][0], e[k][1]);
      float m23 = fmaxf(e[k][2], e[k][3]);
      float m45 = fmaxf(e[k][4], e[k][5]);
      float m67 = fmaxf(e[k][6], e[k][7]);
      float mx  = fmaxf(fmaxf(m01, m23), fmaxf(m45, m67));
      float rS  = __builtin_amdgcn_rcpf(S);
      float rM  = __builtin_amdgcn_rcpf(mx);
      float w0  = a_i[k] * rS;
      w[k] = w0 * mx;  // compensates the rM scaling of e for the epilogue
      #pragma unroll
      for (int j = 0; j < 8; ++j) {
        cc[j] = fmaf(e[k][j], w0, cc[j]);
        e[k][j] *= rM;  // keep row max at 1 -> bounded range
      }
    }

    // ---- block reduction of 8 column partials ----
    // xor over lane bits 3..5: each lane ends with class(l&7) sums of all 8 cols
    #pragma unroll
    for (int j = 0; j < 8; ++j) {
      cc[j] += __shfl_xor(cc[j], 8);
      cc[j] += __shfl_xor(cc[j], 16);
      cc[j] += __shfl_xor(cc[j], 32);
    }
    {
      // lane l contributes (col = l>>3, class = l&7): select cc[l>>3]
      int s = lane >> 3;
      float a0 = (s & 1) ? cc[1] : cc[0];
      float a1 = (s & 1) ? cc[3] : cc[2];
      float a2 = (s & 1) ? cc[5] : cc[4];
      float a3 = (s & 1) ? cc[7] : cc[6];
      float b0 = (s & 2) ? a1 : a0;
      float b1 = (s & 2) ? a3 : a2;
      part[tid] = (s & 4) ? b1 : b0;   // flat = w*64 + col*8 + class
    }
    __syncthreads();

    if (wave == 0) {
      float acc = 0.f;
      #pragma unroll
      for (int q = 0; q < 16; ++q) acc += part[lane + 64 * q];
      // sum over classes (lane bits 0..2); col = lane>>3
      acc += __shfl_xor(acc, 1);
      acc += __shfl_xor(acc, 2);
      acc += __shfl_xor(acc, 4);
      if ((lane & 7) == 0) {
        int j = lane >> 3;
        float c  = fmaxf(acc, 1e-35f);
        float rr = fminf(myb * __builtin_amdgcn_rcpf(c), 1.152921504606847e18f); // clamp ~2^60
        g2 += myl2b - __builtin_amdgcn_logf(c);  // g2 += log2(b) - log2(c)
        rbuf[j]  = rr;
        g2buf[j] = g2;
      }
    }
    __syncthreads();

    {
      float4 r0 = *reinterpret_cast<const float4*>(&rbuf[0]);
      float4 r1 = *reinterpret_cast<const float4*>(&rbuf[4]);
      r[0] = r0.x; r[1] = r0.y; r[2] = r0.z; r[3] = r0.w;
      r[4] = r1.x; r[5] = r1.y; r[6] = r1.z; r[7] = r1.w;
    }
    if (t != NITER - 1) {
      #pragma unroll
      for (int k = 0; k < RPT; ++k)
        #pragma unroll
        for (int j = 0; j < 8; ++j)
          e[k][j] *= r[j];
    }
  }

  // ---- epilogue: P = e * w * r (scale-invariant), then normalize by total ----
  float lsum = 0.f;
  #pragma unroll
  for (int k = 0; k < RPT; ++k) {
    #pragma unroll
    for (int j = 0; j < 8; ++j) {
      float p = e[k][j] * w[k] * r[j];
      e[k][j] = p;
      lsum += p;
    }
  }
  lsum = wsum(lsum);
  if (lane == 0) atomicAdd(&stot, lsum);
  __syncthreads();
  const float itot = __builtin_amdgcn_rcpf(stot);
  #pragma unroll
  for (int k = 0; k < RPT; ++k) {
    float4 o0 = make_float4(e[k][0] * itot, e[k][1] * itot, e[k][2] * itot, e[k][3] * itot);
    float4 o1 = make_float4(e[k][4] * itot, e[k][5] * itot, e[k][6] * itot, e[k][7] * itot);
    float4* op = reinterpret_cast<float4*>(out + (size_t)(tid + NT * RPT / RPT * 0 + tid * 0) * 0 + (size_t)(tid + NT * k) * 8);
    op[0] = o0;
    op[1] = o1;
  }
}

extern "C" void kernel_launch(void* const* d_in, const int* in_sizes, int n_in,
                              void* d_out, int out_size, void* d_ws, size_t ws_size,
                              hipStream_t stream) {
  const float* theta    = (const float*)d_in[0];
  const float* phi      = (const float*)d_in[1];
  const float* sens_raw = (const float*)d_in[2];
  const float* n_raw    = (const float*)d_in[3];
  float* out = (float*)d_out;
  hipLaunchKernelGGL(sinkhorn_k, dim3(1), dim3(NT), 0, stream,
                     theta, phi, sens_raw, n_raw, out);
}

// Round 2
// 387.708 us; speedup vs baseline: 1.6489x; 1.6489x over previous
//
#include <hip/hip_runtime.h>

#define NT 1024
#define RPT 8
#define NITER 200

typedef float v2f __attribute__((ext_vector_type(2)));

// v += dpp-partner(v).  CTRL: 0x128=row_ror:8 (==xor8 in 16-row),
// 0xB1=quad_perm(1,0,3,2)==xor1, 0x4E=quad_perm(2,3,0,1)==xor2,
// 0x141=row_half_mirror (==xor4 once xor1,xor2 are done).
template <int CTRL>
__device__ __forceinline__ float dpp_add(float v) {
  int x = __builtin_amdgcn_update_dpp(0, __float_as_int(v), CTRL, 0xF, 0xF, true);
  return v + __int_as_float(x);
}

__device__ __forceinline__ float wsum(float v) {
  v += __shfl_xor(v, 1);
  v += __shfl_xor(v, 2);
  v += __shfl_xor(v, 4);
  v += __shfl_xor(v, 8);
  v += __shfl_xor(v, 16);
  v += __shfl_xor(v, 32);
  return v;
}

// Sinkhorn, scale-invariant multiplicative form with STATIC e between
// refreshes: e_ij = 2^(K2_ij + g2_j - mx_i) (row max = 1), column scale R_j
// carried separately.  R_new = b_j / ccsum_j needs no history; g2 accumulates
// log2(R) only at refresh points.  P = e * w0 * R, globally normalized.
__global__ __launch_bounds__(NT, 4) void sinkhorn_k(
    const float* __restrict__ theta,
    const float* __restrict__ phi,
    const float* __restrict__ sens_raw,
    const float* __restrict__ n_raw,
    float* __restrict__ out)
{
  constexpr float S1C = 72.13475204444817f;      // (1/EPS) * log2(e)
  constexpr float L2E = 1.4426950408889634f;
  constexpr float CLAMP = 1.152921504606847e18f; // 2^60
  constexpr float ERR0 = 6.25e-2f;               // 2^-4   (bits=2)
  constexpr float ERR1 = 1.5625e-2f;             // 2^-6   (bits=3)
  constexpr float ERR2 = 3.90625e-3f;            // 2^-8   (bits=4)
  constexpr float ERR3 = 9.765625e-4f;           // 2^-10  (bits=5)
  constexpr float ERR4 = 2.44140625e-4f;         // 2^-12  (bits=6)
  constexpr float ERR5 = 1.52587890625e-5f;      // 2^-16  (bits=8)
  constexpr float ERR6 = 9.5367431640625e-7f;    // 2^-20  (bits=10)
  constexpr float ERR7 = 5.9604644775390625e-8f; // 2^-24  (bits=12)

  const int tid  = threadIdx.x;
  const int lane = tid & 63;
  const int wave = tid >> 6;
  const int col  = lane >> 3;   // this lane's owned column for the reduction

  // part2: [buf][col*20 + wave]; stride 20 words makes the 8 float4-read
  // streams (bases 20c words) tile all 32 banks conflict-free.
  __shared__ __align__(16) float part2[2][160];
  __shared__ float sums[2];
  __shared__ float stot;

  if (tid == 0) { sums[0] = 0.f; sums[1] = 0.f; stot = 0.f; }
  __syncthreads();

  // ---- init: per-row loads and global sums over n, sens_raw ----
  float nv[RPT], sv[RPT];
  float pn = 0.f, ps = 0.f;
  #pragma unroll
  for (int k = 0; k < RPT; ++k) {
    int rr = tid + NT * k;
    nv[k] = fmaf(n_raw[rr], 1e5f, 1e3f);
    sv[k] = sens_raw[rr];
    pn += nv[k];
    ps += sv[k];
  }
  pn = wsum(pn);
  ps = wsum(ps);
  if (lane == 0) { atomicAdd(&sums[0], pn); atomicAdd(&sums[1], ps); }
  __syncthreads();
  const float inv_sumn = __builtin_amdgcn_rcpf(sums[0]);
  const float inv_ss   = __builtin_amdgcn_rcpf(sums[1] + 1e-12f);

  float a_i[RPT], rowc[RPT];
  #pragma unroll
  for (int k = 0; k < RPT; ++k) {
    a_i[k]  = nv[k] * inv_sumn;               // row marginal a_i
    rowc[k] = nv[k] * (sv[k] * inv_ss) * S1C; // S1C * n_i * sens_i
  }

  // ---- b = softmax(phi); each lane keeps b for its owned column ----
  float ph[8];
  #pragma unroll
  for (int j = 0; j < 8; ++j) ph[j] = phi[j];
  float pmx = ph[0];
  #pragma unroll
  for (int j = 1; j < 8; ++j) pmx = fmaxf(pmx, ph[j]);
  float bb[8];
  float bs = 0.f;
  #pragma unroll
  for (int j = 0; j < 8; ++j) { bb[j] = __builtin_amdgcn_exp2f((ph[j] - pmx) * L2E); bs += bb[j]; }
  const float ibs = __builtin_amdgcn_rcpf(bs);
  #pragma unroll
  for (int j = 0; j < 8; ++j) bb[j] *= ibs;
  float b_own;
  {
    float a0 = (col & 1) ? bb[1] : bb[0];
    float a1 = (col & 1) ? bb[3] : bb[2];
    float a2 = (col & 1) ? bb[5] : bb[4];
    float a3 = (col & 1) ? bb[7] : bb[6];
    float c0 = (col & 2) ? a1 : a0;
    float c1 = (col & 2) ? a3 : a2;
    b_own = (col & 4) ? c1 : c0;
  }

  v2f e2[RPT][4];
  v2f R2[4];
  float g2r[8];
  float w0k[RPT];
  #pragma unroll
  for (int j = 0; j < 8; ++j) g2r[j] = 0.f;
  R2[0] = (v2f){1.f, 1.f}; R2[1] = (v2f){1.f, 1.f};
  R2[2] = (v2f){1.f, 1.f}; R2[3] = (v2f){1.f, 1.f};

  #pragma unroll 1
  for (int t = 0; t < NITER; ++t) {
    // ---- refresh: absorb log2(R) into g2, rebuild e from theta (L2-hot) ----
    if ((t & 15) == 0) {
      if (t) {
        g2r[0] += __builtin_amdgcn_logf(R2[0].x);
        g2r[1] += __builtin_amdgcn_logf(R2[0].y);
        g2r[2] += __builtin_amdgcn_logf(R2[1].x);
        g2r[3] += __builtin_amdgcn_logf(R2[1].y);
        g2r[4] += __builtin_amdgcn_logf(R2[2].x);
        g2r[5] += __builtin_amdgcn_logf(R2[2].y);
        g2r[6] += __builtin_amdgcn_logf(R2[3].x);
        g2r[7] += __builtin_amdgcn_logf(R2[3].y);
      }
      #pragma unroll
      for (int k = 0; k < RPT; ++k) {
        const float4* tp = reinterpret_cast<const float4*>(theta + (size_t)(tid + NT * k) * 8);
        float4 t0 = tp[0];
        float4 t1 = tp[1];
        float x0 = fmaf(t0.x, S1C, fmaf(-rowc[k], ERR0, g2r[0]));
        float x1 = fmaf(t0.y, S1C, fmaf(-rowc[k], ERR1, g2r[1]));
        float x2 = fmaf(t0.z, S1C, fmaf(-rowc[k], ERR2, g2r[2]));
        float x3 = fmaf(t0.w, S1C, fmaf(-rowc[k], ERR3, g2r[3]));
        float x4 = fmaf(t1.x, S1C, fmaf(-rowc[k], ERR4, g2r[4]));
        float x5 = fmaf(t1.y, S1C, fmaf(-rowc[k], ERR5, g2r[5]));
        float x6 = fmaf(t1.z, S1C, fmaf(-rowc[k], ERR6, g2r[6]));
        float x7 = fmaf(t1.w, S1C, fmaf(-rowc[k], ERR7, g2r[7]));
        float mx = fmaxf(fmaxf(fmaxf(x0, x1), fmaxf(x2, x3)),
                         fmaxf(fmaxf(x4, x5), fmaxf(x6, x7)));
        e2[k][0] = (v2f){__builtin_amdgcn_exp2f(x0 - mx), __builtin_amdgcn_exp2f(x1 - mx)};
        e2[k][1] = (v2f){__builtin_amdgcn_exp2f(x2 - mx), __builtin_amdgcn_exp2f(x3 - mx)};
        e2[k][2] = (v2f){__builtin_amdgcn_exp2f(x4 - mx), __builtin_amdgcn_exp2f(x5 - mx)};
        e2[k][3] = (v2f){__builtin_amdgcn_exp2f(x6 - mx), __builtin_amdgcn_exp2f(x7 - mx)};
      }
      R2[0] = (v2f){1.f, 1.f}; R2[1] = (v2f){1.f, 1.f};
      R2[2] = (v2f){1.f, 1.f}; R2[3] = (v2f){1.f, 1.f};
    }

    // ---- row phase: S_i = e·R (packed), w0 = a/S, cc += e*w0 (packed) ----
    v2f cca = (v2f){0.f, 0.f}, ccb = (v2f){0.f, 0.f};
    v2f ccc = (v2f){0.f, 0.f}, ccd = (v2f){0.f, 0.f};
    #pragma unroll
    for (int k = 0; k < RPT; ++k) {
      v2f sp = e2[k][0] * R2[0];
      sp = sp + e2[k][1] * R2[1];
      sp = sp + e2[k][2] * R2[2];
      sp = sp + e2[k][3] * R2[3];
      float S  = fmaxf(sp.x + sp.y, 1e-37f);
      float w0 = a_i[k] * __builtin_amdgcn_rcpf(S);
      w0k[k] = w0;
      v2f wv = (v2f){w0, w0};
      cca = cca + e2[k][0] * wv;
      ccb = ccb + e2[k][1] * wv;
      ccc = ccc + e2[k][2] * wv;
      ccd = ccd + e2[k][3] * wv;
    }
    float ccf[8] = {cca.x, cca.y, ccb.x, ccb.y, ccc.x, ccc.y, ccd.x, ccd.y};

    // ---- in-wave reduce over lane bits 3,4,5 (xor8 via DPP) ----
    #pragma unroll
    for (int j = 0; j < 8; ++j) {
      ccf[j] = dpp_add<0x128>(ccf[j]);          // xor8 (row_ror:8)
      ccf[j] += __shfl_xor(ccf[j], 16);
      ccf[j] += __shfl_xor(ccf[j], 32);
    }
    // lane (col,class)=(l>>3,l&7) keeps ccf[col]; then sum classes via DPP
    float val;
    {
      float a0 = (col & 1) ? ccf[1] : ccf[0];
      float a1 = (col & 1) ? ccf[3] : ccf[2];
      float a2 = (col & 1) ? ccf[5] : ccf[4];
      float a3 = (col & 1) ? ccf[7] : ccf[6];
      float c0 = (col & 2) ? a1 : a0;
      float c1 = (col & 2) ? a3 : a2;
      val = (col & 4) ? c1 : c0;
    }
    val = dpp_add<0xB1>(val);    // xor1
    val = dpp_add<0x4E>(val);    // xor2
    val = dpp_add<0x141>(val);   // xor4 (valid after xor1,xor2)

    if ((lane & 7) == 0) part2[t & 1][col * 20 + wave] = val;
    __syncthreads();

    // ---- all waves redundantly finish the cross-wave sum (4x b128) ----
    const float4* pp = reinterpret_cast<const float4*>(&part2[t & 1][col * 20]);
    float4 q0 = pp[0], q1 = pp[1], q2 = pp[2], q3 = pp[3];
    float acc = ((q0.x + q0.y) + (q0.z + q0.w)) + ((q1.x + q1.y) + (q1.z + q1.w))
              + ((q2.x + q2.y) + (q2.z + q2.w)) + ((q3.x + q3.y) + (q3.z + q3.w));
    acc = fmaxf(acc, 1e-35f);
    float rown = fminf(b_own * __builtin_amdgcn_rcpf(acc), CLAMP); // R_new = b/ccsum
    float r0 = __shfl(rown, 0),  r1 = __shfl(rown, 8);
    float r2v = __shfl(rown, 16), r3 = __shfl(rown, 24);
    float r4 = __shfl(rown, 32), r5 = __shfl(rown, 40);
    float r6 = __shfl(rown, 48), r7 = __shfl(rown, 56);
    R2[0] = (v2f){r0, r1};
    R2[1] = (v2f){r2v, r3};
    R2[2] = (v2f){r4, r5};
    R2[3] = (v2f){r6, r7};
  }

  // ---- epilogue: P = e * w0 * R, normalize by global total ----
  float lsum = 0.f;
  #pragma unroll
  for (int k = 0; k < RPT; ++k) {
    v2f wv = (v2f){w0k[k], w0k[k]};
    e2[k][0] = e2[k][0] * wv * R2[0];
    e2[k][1] = e2[k][1] * wv * R2[1];
    e2[k][2] = e2[k][2] * wv * R2[2];
    e2[k][3] = e2[k][3] * wv * R2[3];
    lsum += (e2[k][0].x + e2[k][0].y) + (e2[k][1].x + e2[k][1].y)
          + (e2[k][2].x + e2[k][2].y) + (e2[k][3].x + e2[k][3].y);
  }
  lsum = wsum(lsum);
  if (lane == 0) atomicAdd(&stot, lsum);
  __syncthreads();
  const float itot = __builtin_amdgcn_rcpf(stot);
  #pragma unroll
  for (int k = 0; k < RPT; ++k) {
    float4 o0 = make_float4(e2[k][0].x * itot, e2[k][0].y * itot,
                            e2[k][1].x * itot, e2[k][1].y * itot);
    float4 o1 = make_float4(e2[k][2].x * itot, e2[k][2].y * itot,
                            e2[k][3].x * itot, e2[k][3].y * itot);
    float4* op = reinterpret_cast<float4*>(out + (size_t)(tid + NT * k) * 8);
    op[0] = o0;
    op[1] = o1;
  }
}

extern "C" void kernel_launch(void* const* d_in, const int* in_sizes, int n_in,
                              void* d_out, int out_size, void* d_ws, size_t ws_size,
                              hipStream_t stream) {
  const float* theta    = (const float*)d_in[0];
  const float* phi      = (const float*)d_in[1];
  const float* sens_raw = (const float*)d_in[2];
  const float* n_raw    = (const float*)d_in[3];
  float* out = (float*)d_out;
  hipLaunchKernelGGL(sinkhorn_k, dim3(1), dim3(NT), 0, stream,
                     theta, phi, sens_raw, n_raw, out);
}

// Round 5
// 387.677 us; speedup vs baseline: 1.6491x; 1.0001x over previous
//
#include <hip/hip_runtime.h>

#define NT 1024
#define RPT 8
#define NITER 200

typedef float v2f __attribute__((ext_vector_type(2)));

// v += dpp-partner(v).  CTRL: 0x128=row_ror:8 (==xor8 in 16-row),
// 0xB1=quad_perm(1,0,3,2)==xor1, 0x4E=quad_perm(2,3,0,1)==xor2,
// 0x141=row_half_mirror (==xor4 once xor1,xor2 are done).
template <int CTRL>
__device__ __forceinline__ float dpp_add(float v) {
  int x = __builtin_amdgcn_update_dpp(0, __float_as_int(v), CTRL, 0xF, 0xF, true);
  return v + __int_as_float(x);
}

__device__ __forceinline__ float wsum(float v) {
  v += __shfl_xor(v, 1);
  v += __shfl_xor(v, 2);
  v += __shfl_xor(v, 4);
  v += __shfl_xor(v, 8);
  v += __shfl_xor(v, 16);
  v += __shfl_xor(v, 32);
  return v;
}

// Sinkhorn, scale-invariant multiplicative form with STATIC e between
// refreshes: e_ij = 2^(K2_ij + g2_j - mx_i) (row max = 1), column scale R_j
// carried separately.  R_new = b_j / ccsum_j needs no history; g2 accumulates
// log2(R) only at refresh points.  P = e * w0 * R, globally normalized.
// NOTE: this is the round-2 PASSING kernel with exactly one delta:
// explicit v_pk_fma (__builtin_elementwise_fma) in the row phase.
__global__ __launch_bounds__(NT, 4) void sinkhorn_k(
    const float* __restrict__ theta,
    const float* __restrict__ phi,
    const float* __restrict__ sens_raw,
    const float* __restrict__ n_raw,
    float* __restrict__ out)
{
  constexpr float S1C = 72.13475204444817f;      // (1/EPS) * log2(e)
  constexpr float L2E = 1.4426950408889634f;
  constexpr float CLAMP = 1.152921504606847e18f; // 2^60
  constexpr float ERR0 = 6.25e-2f;               // 2^-4   (bits=2)
  constexpr float ERR1 = 1.5625e-2f;             // 2^-6   (bits=3)
  constexpr float ERR2 = 3.90625e-3f;            // 2^-8   (bits=4)
  constexpr float ERR3 = 9.765625e-4f;           // 2^-10  (bits=5)
  constexpr float ERR4 = 2.44140625e-4f;         // 2^-12  (bits=6)
  constexpr float ERR5 = 1.52587890625e-5f;      // 2^-16  (bits=8)
  constexpr float ERR6 = 9.5367431640625e-7f;    // 2^-20  (bits=10)
  constexpr float ERR7 = 5.9604644775390625e-8f; // 2^-24  (bits=12)

  const int tid  = threadIdx.x;
  const int lane = tid & 63;
  const int wave = tid >> 6;
  const int col  = lane >> 3;   // this lane's owned column for the reduction

  // part2: [buf][col*20 + wave]; stride 20 words makes the 8 float4-read
  // streams (bases 20c words) tile all 32 banks conflict-free.
  __shared__ __align__(16) float part2[2][160];
  __shared__ float sums[2];
  __shared__ float stot;

  if (tid == 0) { sums[0] = 0.f; sums[1] = 0.f; stot = 0.f; }
  __syncthreads();

  // ---- init: per-row loads and global sums over n, sens_raw ----
  float nv[RPT], sv[RPT];
  float pn = 0.f, ps = 0.f;
  #pragma unroll
  for (int k = 0; k < RPT; ++k) {
    int rr = tid + NT * k;
    nv[k] = fmaf(n_raw[rr], 1e5f, 1e3f);
    sv[k] = sens_raw[rr];
    pn += nv[k];
    ps += sv[k];
  }
  pn = wsum(pn);
  ps = wsum(ps);
  if (lane == 0) { atomicAdd(&sums[0], pn); atomicAdd(&sums[1], ps); }
  __syncthreads();
  const float inv_sumn = __builtin_amdgcn_rcpf(sums[0]);
  const float inv_ss   = __builtin_amdgcn_rcpf(sums[1] + 1e-12f);

  float a_i[RPT], rowc[RPT];
  #pragma unroll
  for (int k = 0; k < RPT; ++k) {
    a_i[k]  = nv[k] * inv_sumn;               // row marginal a_i
    rowc[k] = nv[k] * (sv[k] * inv_ss) * S1C; // S1C * n_i * sens_i
  }

  // ---- b = softmax(phi); each lane keeps b for its owned column ----
  float ph[8];
  #pragma unroll
  for (int j = 0; j < 8; ++j) ph[j] = phi[j];
  float pmx = ph[0];
  #pragma unroll
  for (int j = 1; j < 8; ++j) pmx = fmaxf(pmx, ph[j]);
  float bb[8];
  float bs = 0.f;
  #pragma unroll
  for (int j = 0; j < 8; ++j) { bb[j] = __builtin_amdgcn_exp2f((ph[j] - pmx) * L2E); bs += bb[j]; }
  const float ibs = __builtin_amdgcn_rcpf(bs);
  #pragma unroll
  for (int j = 0; j < 8; ++j) bb[j] *= ibs;
  float b_own;
  {
    float a0 = (col & 1) ? bb[1] : bb[0];
    float a1 = (col & 1) ? bb[3] : bb[2];
    float a2 = (col & 1) ? bb[5] : bb[4];
    float a3 = (col & 1) ? bb[7] : bb[6];
    float c0 = (col & 2) ? a1 : a0;
    float c1 = (col & 2) ? a3 : a2;
    b_own = (col & 4) ? c1 : c0;
  }

  v2f e2[RPT][4];
  v2f R2[4];
  float g2r[8];
  float w0k[RPT];
  #pragma unroll
  for (int j = 0; j < 8; ++j) g2r[j] = 0.f;
  R2[0] = (v2f){1.f, 1.f}; R2[1] = (v2f){1.f, 1.f};
  R2[2] = (v2f){1.f, 1.f}; R2[3] = (v2f){1.f, 1.f};

  #pragma unroll 1
  for (int t = 0; t < NITER; ++t) {
    // ---- refresh: absorb log2(R) into g2, rebuild e from theta (L2-hot) ----
    if ((t & 15) == 0) {
      if (t) {
        g2r[0] += __builtin_amdgcn_logf(R2[0].x);
        g2r[1] += __builtin_amdgcn_logf(R2[0].y);
        g2r[2] += __builtin_amdgcn_logf(R2[1].x);
        g2r[3] += __builtin_amdgcn_logf(R2[1].y);
        g2r[4] += __builtin_amdgcn_logf(R2[2].x);
        g2r[5] += __builtin_amdgcn_logf(R2[2].y);
        g2r[6] += __builtin_amdgcn_logf(R2[3].x);
        g2r[7] += __builtin_amdgcn_logf(R2[3].y);
      }
      #pragma unroll
      for (int k = 0; k < RPT; ++k) {
        const float4* tp = reinterpret_cast<const float4*>(theta + (size_t)(tid + NT * k) * 8);
        float4 t0 = tp[0];
        float4 t1 = tp[1];
        float x0 = fmaf(t0.x, S1C, fmaf(-rowc[k], ERR0, g2r[0]));
        float x1 = fmaf(t0.y, S1C, fmaf(-rowc[k], ERR1, g2r[1]));
        float x2 = fmaf(t0.z, S1C, fmaf(-rowc[k], ERR2, g2r[2]));
        float x3 = fmaf(t0.w, S1C, fmaf(-rowc[k], ERR3, g2r[3]));
        float x4 = fmaf(t1.x, S1C, fmaf(-rowc[k], ERR4, g2r[4]));
        float x5 = fmaf(t1.y, S1C, fmaf(-rowc[k], ERR5, g2r[5]));
        float x6 = fmaf(t1.z, S1C, fmaf(-rowc[k], ERR6, g2r[6]));
        float x7 = fmaf(t1.w, S1C, fmaf(-rowc[k], ERR7, g2r[7]));
        float mx = fmaxf(fmaxf(fmaxf(x0, x1), fmaxf(x2, x3)),
                         fmaxf(fmaxf(x4, x5), fmaxf(x6, x7)));
        e2[k][0] = (v2f){__builtin_amdgcn_exp2f(x0 - mx), __builtin_amdgcn_exp2f(x1 - mx)};
        e2[k][1] = (v2f){__builtin_amdgcn_exp2f(x2 - mx), __builtin_amdgcn_exp2f(x3 - mx)};
        e2[k][2] = (v2f){__builtin_amdgcn_exp2f(x4 - mx), __builtin_amdgcn_exp2f(x5 - mx)};
        e2[k][3] = (v2f){__builtin_amdgcn_exp2f(x6 - mx), __builtin_amdgcn_exp2f(x7 - mx)};
      }
      R2[0] = (v2f){1.f, 1.f}; R2[1] = (v2f){1.f, 1.f};
      R2[2] = (v2f){1.f, 1.f}; R2[3] = (v2f){1.f, 1.f};
    }

    // ---- row phase: S_i = e·R (pk_fma), w0 = a/S, cc += e*w0 (pk_fma) ----
    v2f cca = (v2f){0.f, 0.f}, ccb = (v2f){0.f, 0.f};
    v2f ccc = (v2f){0.f, 0.f}, ccd = (v2f){0.f, 0.f};
    #pragma unroll
    for (int k = 0; k < RPT; ++k) {
      v2f sp = e2[k][0] * R2[0];
      sp = __builtin_elementwise_fma(e2[k][1], R2[1], sp);
      sp = __builtin_elementwise_fma(e2[k][2], R2[2], sp);
      sp = __builtin_elementwise_fma(e2[k][3], R2[3], sp);
      float S  = fmaxf(sp.x + sp.y, 1e-37f);
      float w0 = a_i[k] * __builtin_amdgcn_rcpf(S);
      w0k[k] = w0;
      v2f wv = (v2f){w0, w0};
      cca = __builtin_elementwise_fma(e2[k][0], wv, cca);
      ccb = __builtin_elementwise_fma(e2[k][1], wv, ccb);
      ccc = __builtin_elementwise_fma(e2[k][2], wv, ccc);
      ccd = __builtin_elementwise_fma(e2[k][3], wv, ccd);
    }
    float ccf[8] = {cca.x, cca.y, ccb.x, ccb.y, ccc.x, ccc.y, ccd.x, ccd.y};

    // ---- in-wave reduce over lane bits 3,4,5 (xor8 via DPP) ----
    #pragma unroll
    for (int j = 0; j < 8; ++j) {
      ccf[j] = dpp_add<0x128>(ccf[j]);          // xor8 (row_ror:8)
      ccf[j] += __shfl_xor(ccf[j], 16);
      ccf[j] += __shfl_xor(ccf[j], 32);
    }
    // lane (col,class)=(l>>3,l&7) keeps ccf[col]; then sum classes via DPP
    float val;
    {
      float a0 = (col & 1) ? ccf[1] : ccf[0];
      float a1 = (col & 1) ? ccf[3] : ccf[2];
      float a2 = (col & 1) ? ccf[5] : ccf[4];
      float a3 = (col & 1) ? ccf[7] : ccf[6];
      float c0 = (col & 2) ? a1 : a0;
      float c1 = (col & 2) ? a3 : a2;
      val = (col & 4) ? c1 : c0;
    }
    val = dpp_add<0xB1>(val);    // xor1
    val = dpp_add<0x4E>(val);    // xor2
    val = dpp_add<0x141>(val);   // xor4 (valid after xor1,xor2)

    if ((lane & 7) == 0) part2[t & 1][col * 20 + wave] = val;
    __syncthreads();

    // ---- all waves redundantly finish the cross-wave sum (4x b128) ----
    const float4* pp = reinterpret_cast<const float4*>(&part2[t & 1][col * 20]);
    float4 q0 = pp[0], q1 = pp[1], q2 = pp[2], q3 = pp[3];
    float acc = ((q0.x + q0.y) + (q0.z + q0.w)) + ((q1.x + q1.y) + (q1.z + q1.w))
              + ((q2.x + q2.y) + (q2.z + q2.w)) + ((q3.x + q3.y) + (q3.z + q3.w));
    acc = fmaxf(acc, 1e-35f);
    float rown = fminf(b_own * __builtin_amdgcn_rcpf(acc), CLAMP); // R_new = b/ccsum
    float r0 = __shfl(rown, 0),  r1 = __shfl(rown, 8);
    float r2v = __shfl(rown, 16), r3 = __shfl(rown, 24);
    float r4 = __shfl(rown, 32), r5 = __shfl(rown, 40);
    float r6 = __shfl(rown, 48), r7 = __shfl(rown, 56);
    R2[0] = (v2f){r0, r1};
    R2[1] = (v2f){r2v, r3};
    R2[2] = (v2f){r4, r5};
    R2[3] = (v2f){r6, r7};
  }

  // ---- epilogue: P = e * w0 * R, normalize by global total ----
  float lsum = 0.f;
  #pragma unroll
  for (int k = 0; k < RPT; ++k) {
    v2f wv = (v2f){w0k[k], w0k[k]};
    e2[k][0] = e2[k][0] * wv * R2[0];
    e2[k][1] = e2[k][1] * wv * R2[1];
    e2[k][2] = e2[k][2] * wv * R2[2];
    e2[k][3] = e2[k][3] * wv * R2[3];
    lsum += (e2[k][0].x + e2[k][0].y) + (e2[k][1].x + e2[k][1].y)
          + (e2[k][2].x + e2[k][2].y) + (e2[k][3].x + e2[k][3].y);
  }
  lsum = wsum(lsum);
  if (lane == 0) atomicAdd(&stot, lsum);
  __syncthreads();
  const float itot = __builtin_amdgcn_rcpf(stot);
  #pragma unroll
  for (int k = 0; k < RPT; ++k) {
    float4 o0 = make_float4(e2[k][0].x * itot, e2[k][0].y * itot,
                            e2[k][1].x * itot, e2[k][1].y * itot);
    float4 o1 = make_float4(e2[k][2].x * itot, e2[k][2].y * itot,
                            e2[k][3].x * itot, e2[k][3].y * itot);
    float4* op = reinterpret_cast<float4*>(out + (size_t)(tid + NT * k) * 8);
    op[0] = o0;
    op[1] = o1;
  }
}

extern "C" void kernel_launch(void* const* d_in, const int* in_sizes, int n_in,
                              void* d_out, int out_size, void* d_ws, size_t ws_size,
                              hipStream_t stream) {
  const float* theta    = (const float*)d_in[0];
  const float* phi      = (const float*)d_in[1];
  const float* sens_raw = (const float*)d_in[2];
  const float* n_raw    = (const float*)d_in[3];
  float* out = (float*)d_out;
  hipLaunchKernelGGL(sinkhorn_k, dim3(1), dim3(NT), 0, stream,
                     theta, phi, sens_raw, n_raw, out);
}

// Round 6
// 358.331 us; speedup vs baseline: 1.7841x; 1.0819x over previous
//
#include <hip/hip_runtime.h>

#define NT 1024
#define RPT 8
#define NITER 200

typedef float v2f __attribute__((ext_vector_type(2)));

// v += dpp-partner(v).  CTRL: 0x128=row_ror:8 (==xor8 in 16-row),
// 0xB1=quad_perm(1,0,3,2)==xor1, 0x4E=quad_perm(2,3,0,1)==xor2,
// 0x141=row_half_mirror (==xor4 once xor1,xor2 are done).
template <int CTRL>
__device__ __forceinline__ float dpp_add(float v) {
  int x = __builtin_amdgcn_update_dpp(0, __float_as_int(v), CTRL, 0xF, 0xF, true);
  return v + __int_as_float(x);
}

__device__ __forceinline__ float wsum(float v) {
  v += __shfl_xor(v, 1);
  v += __shfl_xor(v, 2);
  v += __shfl_xor(v, 4);
  v += __shfl_xor(v, 8);
  v += __shfl_xor(v, 16);
  v += __shfl_xor(v, 32);
  return v;
}

// Sinkhorn, scale-invariant multiplicative form with STATIC e between
// refreshes. Round-5 passing kernel with two deltas:
//  (1) amdgpu_waves_per_eu(4,4): target exactly 4 waves/EU -> 128 arch VGPRs,
//      kill AGPR-spill moves (we only ever have one 1024-thread block).
//  (2) fold-and-halve cross-lane reduction (30 ops vs 50), validated
//      primitives only (dpp_add ctrls, shfl_xor 16/32, cndmask).
__global__ void __launch_bounds__(NT)
__attribute__((amdgpu_waves_per_eu(4, 4)))
sinkhorn_k(
    const float* __restrict__ theta,
    const float* __restrict__ phi,
    const float* __restrict__ sens_raw,
    const float* __restrict__ n_raw,
    float* __restrict__ out)
{
  constexpr float S1C = 72.13475204444817f;      // (1/EPS) * log2(e)
  constexpr float L2E = 1.4426950408889634f;
  constexpr float CLAMP = 1.152921504606847e18f; // 2^60
  constexpr float ERR0 = 6.25e-2f;               // 2^-4   (bits=2)
  constexpr float ERR1 = 1.5625e-2f;             // 2^-6   (bits=3)
  constexpr float ERR2 = 3.90625e-3f;            // 2^-8   (bits=4)
  constexpr float ERR3 = 9.765625e-4f;           // 2^-10  (bits=5)
  constexpr float ERR4 = 2.44140625e-4f;         // 2^-12  (bits=6)
  constexpr float ERR5 = 1.52587890625e-5f;      // 2^-16  (bits=8)
  constexpr float ERR6 = 9.5367431640625e-7f;    // 2^-20  (bits=10)
  constexpr float ERR7 = 5.9604644775390625e-8f; // 2^-24  (bits=12)

  const int tid  = threadIdx.x;
  const int lane = tid & 63;
  const int wave = tid >> 6;
  const int col  = lane >> 3;   // reader-side column (post-barrier)

  // writer-side column after the fold tree: bit-reversed group index
  const int cw = (((lane >> 3) & 1) << 2) | (((lane >> 4) & 1) << 1) | ((lane >> 5) & 1);
  const int widx = cw * 20 + wave;

  // part2: [buf][col*20 + wave]; stride 20 words keeps the 8 float4-read
  // streams conflict-free.
  __shared__ __align__(16) float part2[2][160];
  __shared__ float sums[2];
  __shared__ float stot;

  if (tid == 0) { sums[0] = 0.f; sums[1] = 0.f; stot = 0.f; }
  __syncthreads();

  // ---- init: per-row loads and global sums over n, sens_raw ----
  float nv[RPT], sv[RPT];
  float pn = 0.f, ps = 0.f;
  #pragma unroll
  for (int k = 0; k < RPT; ++k) {
    int rr = tid + NT * k;
    nv[k] = fmaf(n_raw[rr], 1e5f, 1e3f);
    sv[k] = sens_raw[rr];
    pn += nv[k];
    ps += sv[k];
  }
  pn = wsum(pn);
  ps = wsum(ps);
  if (lane == 0) { atomicAdd(&sums[0], pn); atomicAdd(&sums[1], ps); }
  __syncthreads();
  const float inv_sumn = __builtin_amdgcn_rcpf(sums[0]);
  const float inv_ss   = __builtin_amdgcn_rcpf(sums[1] + 1e-12f);

  float a_i[RPT], rowc[RPT];
  #pragma unroll
  for (int k = 0; k < RPT; ++k) {
    a_i[k]  = nv[k] * inv_sumn;               // row marginal a_i
    rowc[k] = nv[k] * (sv[k] * inv_ss) * S1C; // S1C * n_i * sens_i
  }

  // ---- b = softmax(phi); each lane keeps b for its reader column ----
  float ph[8];
  #pragma unroll
  for (int j = 0; j < 8; ++j) ph[j] = phi[j];
  float pmx = ph[0];
  #pragma unroll
  for (int j = 1; j < 8; ++j) pmx = fmaxf(pmx, ph[j]);
  float bb[8];
  float bs = 0.f;
  #pragma unroll
  for (int j = 0; j < 8; ++j) { bb[j] = __builtin_amdgcn_exp2f((ph[j] - pmx) * L2E); bs += bb[j]; }
  const float ibs = __builtin_amdgcn_rcpf(bs);
  #pragma unroll
  for (int j = 0; j < 8; ++j) bb[j] *= ibs;
  float b_own;
  {
    float a0 = (col & 1) ? bb[1] : bb[0];
    float a1 = (col & 1) ? bb[3] : bb[2];
    float a2 = (col & 1) ? bb[5] : bb[4];
    float a3 = (col & 1) ? bb[7] : bb[6];
    float c0 = (col & 2) ? a1 : a0;
    float c1 = (col & 2) ? a3 : a2;
    b_own = (col & 4) ? c1 : c0;
  }

  v2f e2[RPT][4];
  v2f R2[4];
  float g2r[8];
  float w0k[RPT];
  #pragma unroll
  for (int j = 0; j < 8; ++j) g2r[j] = 0.f;
  R2[0] = (v2f){1.f, 1.f}; R2[1] = (v2f){1.f, 1.f};
  R2[2] = (v2f){1.f, 1.f}; R2[3] = (v2f){1.f, 1.f};

  #pragma unroll 1
  for (int t = 0; t < NITER; ++t) {
    // ---- refresh: absorb log2(R) into g2, rebuild e from theta (L2-hot) ----
    if ((t & 15) == 0) {
      if (t) {
        g2r[0] += __builtin_amdgcn_logf(R2[0].x);
        g2r[1] += __builtin_amdgcn_logf(R2[0].y);
        g2r[2] += __builtin_amdgcn_logf(R2[1].x);
        g2r[3] += __builtin_amdgcn_logf(R2[1].y);
        g2r[4] += __builtin_amdgcn_logf(R2[2].x);
        g2r[5] += __builtin_amdgcn_logf(R2[2].y);
        g2r[6] += __builtin_amdgcn_logf(R2[3].x);
        g2r[7] += __builtin_amdgcn_logf(R2[3].y);
      }
      #pragma unroll
      for (int k = 0; k < RPT; ++k) {
        const float4* tp = reinterpret_cast<const float4*>(theta + (size_t)(tid + NT * k) * 8);
        float4 t0 = tp[0];
        float4 t1 = tp[1];
        float x0 = fmaf(t0.x, S1C, fmaf(-rowc[k], ERR0, g2r[0]));
        float x1 = fmaf(t0.y, S1C, fmaf(-rowc[k], ERR1, g2r[1]));
        float x2 = fmaf(t0.z, S1C, fmaf(-rowc[k], ERR2, g2r[2]));
        float x3 = fmaf(t0.w, S1C, fmaf(-rowc[k], ERR3, g2r[3]));
        float x4 = fmaf(t1.x, S1C, fmaf(-rowc[k], ERR4, g2r[4]));
        float x5 = fmaf(t1.y, S1C, fmaf(-rowc[k], ERR5, g2r[5]));
        float x6 = fmaf(t1.z, S1C, fmaf(-rowc[k], ERR6, g2r[6]));
        float x7 = fmaf(t1.w, S1C, fmaf(-rowc[k], ERR7, g2r[7]));
        float mx = fmaxf(fmaxf(fmaxf(x0, x1), fmaxf(x2, x3)),
                         fmaxf(fmaxf(x4, x5), fmaxf(x6, x7)));
        e2[k][0] = (v2f){__builtin_amdgcn_exp2f(x0 - mx), __builtin_amdgcn_exp2f(x1 - mx)};
        e2[k][1] = (v2f){__builtin_amdgcn_exp2f(x2 - mx), __builtin_amdgcn_exp2f(x3 - mx)};
        e2[k][2] = (v2f){__builtin_amdgcn_exp2f(x4 - mx), __builtin_amdgcn_exp2f(x5 - mx)};
        e2[k][3] = (v2f){__builtin_amdgcn_exp2f(x6 - mx), __builtin_amdgcn_exp2f(x7 - mx)};
      }
      R2[0] = (v2f){1.f, 1.f}; R2[1] = (v2f){1.f, 1.f};
      R2[2] = (v2f){1.f, 1.f}; R2[3] = (v2f){1.f, 1.f};
    }

    // ---- row phase: S_i = e·R (pk_fma), w0 = a/S, cc += e*w0 (pk_fma) ----
    v2f cca = (v2f){0.f, 0.f}, ccb = (v2f){0.f, 0.f};
    v2f ccc = (v2f){0.f, 0.f}, ccd = (v2f){0.f, 0.f};
    #pragma unroll
    for (int k = 0; k < RPT; ++k) {
      v2f sp = e2[k][0] * R2[0];
      sp = __builtin_elementwise_fma(e2[k][1], R2[1], sp);
      sp = __builtin_elementwise_fma(e2[k][2], R2[2], sp);
      sp = __builtin_elementwise_fma(e2[k][3], R2[3], sp);
      float S  = fmaxf(sp.x + sp.y, 1e-37f);
      float w0 = a_i[k] * __builtin_amdgcn_rcpf(S);
      w0k[k] = w0;
      v2f wv = (v2f){w0, w0};
      cca = __builtin_elementwise_fma(e2[k][0], wv, cca);
      ccb = __builtin_elementwise_fma(e2[k][1], wv, ccb);
      ccc = __builtin_elementwise_fma(e2[k][2], wv, ccc);
      ccd = __builtin_elementwise_fma(e2[k][3], wv, ccd);
    }

    // ---- fold-and-halve reduction over lane bits 3,4,5 ----
    // step 1: xor8 via DPP on all 8 cols, then keep 4 by bit3
    float s0 = dpp_add<0x128>(cca.x);
    float s1 = dpp_add<0x128>(cca.y);
    float s2 = dpp_add<0x128>(ccb.x);
    float s3 = dpp_add<0x128>(ccb.y);
    float s4 = dpp_add<0x128>(ccc.x);
    float s5 = dpp_add<0x128>(ccc.y);
    float s6 = dpp_add<0x128>(ccd.x);
    float s7 = dpp_add<0x128>(ccd.y);
    bool hb3 = (lane & 8) != 0;
    float k0 = hb3 ? s4 : s0;
    float k1 = hb3 ? s5 : s1;
    float k2 = hb3 ? s6 : s2;
    float k3 = hb3 ? s7 : s3;
    // step 2: xor16, keep 2 by bit4
    k0 += __shfl_xor(k0, 16);
    k1 += __shfl_xor(k1, 16);
    k2 += __shfl_xor(k2, 16);
    k3 += __shfl_xor(k3, 16);
    bool hb4 = (lane & 16) != 0;
    float u0 = hb4 ? k2 : k0;
    float u1 = hb4 ? k3 : k1;
    // step 3: xor32, keep 1 by bit5
    u0 += __shfl_xor(u0, 32);
    u1 += __shfl_xor(u1, 32);
    float val = ((lane & 32) != 0) ? u1 : u0;
    // sum the 8 classes (lane bits 0..2)
    val = dpp_add<0xB1>(val);    // xor1
    val = dpp_add<0x4E>(val);    // xor2
    val = dpp_add<0x141>(val);   // xor4 (valid after xor1,xor2)

    if ((lane & 7) == 0) part2[t & 1][widx] = val;
    __syncthreads();

    // ---- all waves redundantly finish the cross-wave sum (4x b128) ----
    const float4* pp = reinterpret_cast<const float4*>(&part2[t & 1][col * 20]);
    float4 q0 = pp[0], q1 = pp[1], q2 = pp[2], q3 = pp[3];
    float acc = ((q0.x + q0.y) + (q0.z + q0.w)) + ((q1.x + q1.y) + (q1.z + q1.w))
              + ((q2.x + q2.y) + (q2.z + q2.w)) + ((q3.x + q3.y) + (q3.z + q3.w));
    acc = fmaxf(acc, 1e-35f);
    float rown = fminf(b_own * __builtin_amdgcn_rcpf(acc), CLAMP); // R_new = b/ccsum
    float r0 = __shfl(rown, 0),  r1 = __shfl(rown, 8);
    float r2v = __shfl(rown, 16), r3 = __shfl(rown, 24);
    float r4 = __shfl(rown, 32), r5 = __shfl(rown, 40);
    float r6 = __shfl(rown, 48), r7 = __shfl(rown, 56);
    R2[0] = (v2f){r0, r1};
    R2[1] = (v2f){r2v, r3};
    R2[2] = (v2f){r4, r5};
    R2[3] = (v2f){r6, r7};
  }

  // ---- epilogue: P = e * w0 * R, normalize by global total ----
  float lsum = 0.f;
  #pragma unroll
  for (int k = 0; k < RPT; ++k) {
    v2f wv = (v2f){w0k[k], w0k[k]};
    e2[k][0] = e2[k][0] * wv * R2[0];
    e2[k][1] = e2[k][1] * wv * R2[1];
    e2[k][2] = e2[k][2] * wv * R2[2];
    e2[k][3] = e2[k][3] * wv * R2[3];
    lsum += (e2[k][0].x + e2[k][0].y) + (e2[k][1].x + e2[k][1].y)
          + (e2[k][2].x + e2[k][2].y) + (e2[k][3].x + e2[k][3].y);
  }
  lsum = wsum(lsum);
  if (lane == 0) atomicAdd(&stot, lsum);
  __syncthreads();
  const float itot = __builtin_amdgcn_rcpf(stot);
  #pragma unroll
  for (int k = 0; k < RPT; ++k) {
    float4 o0 = make_float4(e2[k][0].x * itot, e2[k][0].y * itot,
                            e2[k][1].x * itot, e2[k][1].y * itot);
    float4 o1 = make_float4(e2[k][2].x * itot, e2[k][2].y * itot,
                            e2[k][3].x * itot, e2[k][3].y * itot);
    float4* op = reinterpret_cast<float4*>(out + (size_t)(tid + NT * k) * 8);
    op[0] = o0;
    op[1] = o1;
  }
}

extern "C" void kernel_launch(void* const* d_in, const int* in_sizes, int n_in,
                              void* d_out, int out_size, void* d_ws, size_t ws_size,
                              hipStream_t stream) {
  const float* theta    = (const float*)d_in[0];
  const float* phi      = (const float*)d_in[1];
  const float* sens_raw = (const float*)d_in[2];
  const float* n_raw    = (const float*)d_in[3];
  float* out = (float*)d_out;
  hipLaunchKernelGGL(sinkhorn_k, dim3(1), dim3(NT), 0, stream,
                     theta, phi, sens_raw, n_raw, out);
}

// Round 7
// 352.278 us; speedup vs baseline: 1.8148x; 1.0172x over previous
//
#include <hip/hip_runtime.h>

#define NT 1024
#define RPT 8
#define NITER 200

typedef float v2f __attribute__((ext_vector_type(2)));

// v += dpp-partner(v).  CTRL: 0x128=row_ror:8 (==xor8 in 16-row),
// 0xB1=quad_perm(1,0,3,2)==xor1, 0x4E=quad_perm(2,3,0,1)==xor2,
// 0x141=row_half_mirror (==xor4 once xor1,xor2 are done).
template <int CTRL>
__device__ __forceinline__ float dpp_add(float v) {
  int x = __builtin_amdgcn_update_dpp(0, __float_as_int(v), CTRL, 0xF, 0xF, true);
  return v + __int_as_float(x);
}

__device__ __forceinline__ float wsum(float v) {
  v += __shfl_xor(v, 1);
  v += __shfl_xor(v, 2);
  v += __shfl_xor(v, 4);
  v += __shfl_xor(v, 8);
  v += __shfl_xor(v, 16);
  v += __shfl_xor(v, 32);
  return v;
}

// Sinkhorn, scale-invariant multiplicative form with STATIC e between
// refreshes. Round-6 passing kernel with one structural delta:
// the post-barrier tail. Wave 0 alone finishes the cross-wave column sum
// and publishes R via rbuf[8] (round-1-validated pattern); all lanes then
// fetch R with 2 broadcast ds_read_b128 instead of 8 ds_bpermute shuffles.
// part2/rbuf single-buffered (two barriers/iter make it safe).
__global__ void __launch_bounds__(NT)
__attribute__((amdgpu_waves_per_eu(4, 4)))
sinkhorn_k(
    const float* __restrict__ theta,
    const float* __restrict__ phi,
    const float* __restrict__ sens_raw,
    const float* __restrict__ n_raw,
    float* __restrict__ out)
{
  constexpr float S1C = 72.13475204444817f;      // (1/EPS) * log2(e)
  constexpr float L2E = 1.4426950408889634f;
  constexpr float CLAMP = 1.152921504606847e18f; // 2^60
  constexpr float ERR0 = 6.25e-2f;               // 2^-4   (bits=2)
  constexpr float ERR1 = 1.5625e-2f;             // 2^-6   (bits=3)
  constexpr float ERR2 = 3.90625e-3f;            // 2^-8   (bits=4)
  constexpr float ERR3 = 9.765625e-4f;           // 2^-10  (bits=5)
  constexpr float ERR4 = 2.44140625e-4f;         // 2^-12  (bits=6)
  constexpr float ERR5 = 1.52587890625e-5f;      // 2^-16  (bits=8)
  constexpr float ERR6 = 9.5367431640625e-7f;    // 2^-20  (bits=10)
  constexpr float ERR7 = 5.9604644775390625e-8f; // 2^-24  (bits=12)

  const int tid  = threadIdx.x;
  const int lane = tid & 63;
  const int wave = tid >> 6;
  const int col  = lane >> 3;   // reader-side column (post-barrier)

  // writer-side column after the fold tree: bit-reversed group index
  const int cw = (((lane >> 3) & 1) << 2) | (((lane >> 4) & 1) << 1) | ((lane >> 5) & 1);
  const int widx = cw * 20 + wave;

  // part2: [col*20 + wave]; stride 20 words keeps the 8 float4-read
  // streams conflict-free.
  __shared__ __align__(16) float part2[160];
  __shared__ __align__(16) float rbuf[8];
  __shared__ float sums[2];
  __shared__ float stot;

  if (tid == 0) { sums[0] = 0.f; sums[1] = 0.f; stot = 0.f; }
  __syncthreads();

  // ---- init: per-row loads and global sums over n, sens_raw ----
  float nv[RPT], sv[RPT];
  float pn = 0.f, ps = 0.f;
  #pragma unroll
  for (int k = 0; k < RPT; ++k) {
    int rr = tid + NT * k;
    nv[k] = fmaf(n_raw[rr], 1e5f, 1e3f);
    sv[k] = sens_raw[rr];
    pn += nv[k];
    ps += sv[k];
  }
  pn = wsum(pn);
  ps = wsum(ps);
  if (lane == 0) { atomicAdd(&sums[0], pn); atomicAdd(&sums[1], ps); }
  __syncthreads();
  const float inv_sumn = __builtin_amdgcn_rcpf(sums[0]);
  const float inv_ss   = __builtin_amdgcn_rcpf(sums[1] + 1e-12f);

  float a_i[RPT], rowc[RPT];
  #pragma unroll
  for (int k = 0; k < RPT; ++k) {
    a_i[k]  = nv[k] * inv_sumn;               // row marginal a_i
    rowc[k] = nv[k] * (sv[k] * inv_ss) * S1C; // S1C * n_i * sens_i
  }

  // ---- b = softmax(phi); each lane keeps b for its reader column ----
  float ph[8];
  #pragma unroll
  for (int j = 0; j < 8; ++j) ph[j] = phi[j];
  float pmx = ph[0];
  #pragma unroll
  for (int j = 1; j < 8; ++j) pmx = fmaxf(pmx, ph[j]);
  float bb[8];
  float bs = 0.f;
  #pragma unroll
  for (int j = 0; j < 8; ++j) { bb[j] = __builtin_amdgcn_exp2f((ph[j] - pmx) * L2E); bs += bb[j]; }
  const float ibs = __builtin_amdgcn_rcpf(bs);
  #pragma unroll
  for (int j = 0; j < 8; ++j) bb[j] *= ibs;
  float b_own;
  {
    float a0 = (col & 1) ? bb[1] : bb[0];
    float a1 = (col & 1) ? bb[3] : bb[2];
    float a2 = (col & 1) ? bb[5] : bb[4];
    float a3 = (col & 1) ? bb[7] : bb[6];
    float c0 = (col & 2) ? a1 : a0;
    float c1 = (col & 2) ? a3 : a2;
    b_own = (col & 4) ? c1 : c0;
  }

  v2f e2[RPT][4];
  v2f R2[4];
  float g2r[8];
  float w0k[RPT];
  #pragma unroll
  for (int j = 0; j < 8; ++j) g2r[j] = 0.f;
  R2[0] = (v2f){1.f, 1.f}; R2[1] = (v2f){1.f, 1.f};
  R2[2] = (v2f){1.f, 1.f}; R2[3] = (v2f){1.f, 1.f};

  #pragma unroll 1
  for (int t = 0; t < NITER; ++t) {
    // ---- refresh: absorb log2(R) into g2, rebuild e from theta (L2-hot) ----
    if ((t & 15) == 0) {
      if (t) {
        g2r[0] += __builtin_amdgcn_logf(R2[0].x);
        g2r[1] += __builtin_amdgcn_logf(R2[0].y);
        g2r[2] += __builtin_amdgcn_logf(R2[1].x);
        g2r[3] += __builtin_amdgcn_logf(R2[1].y);
        g2r[4] += __builtin_amdgcn_logf(R2[2].x);
        g2r[5] += __builtin_amdgcn_logf(R2[2].y);
        g2r[6] += __builtin_amdgcn_logf(R2[3].x);
        g2r[7] += __builtin_amdgcn_logf(R2[3].y);
      }
      #pragma unroll
      for (int k = 0; k < RPT; ++k) {
        const float4* tp = reinterpret_cast<const float4*>(theta + (size_t)(tid + NT * k) * 8);
        float4 t0 = tp[0];
        float4 t1 = tp[1];
        float x0 = fmaf(t0.x, S1C, fmaf(-rowc[k], ERR0, g2r[0]));
        float x1 = fmaf(t0.y, S1C, fmaf(-rowc[k], ERR1, g2r[1]));
        float x2 = fmaf(t0.z, S1C, fmaf(-rowc[k], ERR2, g2r[2]));
        float x3 = fmaf(t0.w, S1C, fmaf(-rowc[k], ERR3, g2r[3]));
        float x4 = fmaf(t1.x, S1C, fmaf(-rowc[k], ERR4, g2r[4]));
        float x5 = fmaf(t1.y, S1C, fmaf(-rowc[k], ERR5, g2r[5]));
        float x6 = fmaf(t1.z, S1C, fmaf(-rowc[k], ERR6, g2r[6]));
        float x7 = fmaf(t1.w, S1C, fmaf(-rowc[k], ERR7, g2r[7]));
        float mx = fmaxf(fmaxf(fmaxf(x0, x1), fmaxf(x2, x3)),
                         fmaxf(fmaxf(x4, x5), fmaxf(x6, x7)));
        e2[k][0] = (v2f){__builtin_amdgcn_exp2f(x0 - mx), __builtin_amdgcn_exp2f(x1 - mx)};
        e2[k][1] = (v2f){__builtin_amdgcn_exp2f(x2 - mx), __builtin_amdgcn_exp2f(x3 - mx)};
        e2[k][2] = (v2f){__builtin_amdgcn_exp2f(x4 - mx), __builtin_amdgcn_exp2f(x5 - mx)};
        e2[k][3] = (v2f){__builtin_amdgcn_exp2f(x6 - mx), __builtin_amdgcn_exp2f(x7 - mx)};
      }
      R2[0] = (v2f){1.f, 1.f}; R2[1] = (v2f){1.f, 1.f};
      R2[2] = (v2f){1.f, 1.f}; R2[3] = (v2f){1.f, 1.f};
    }

    // ---- row phase: S_i = e·R (pk_fma), w0 = a/S, cc += e*w0 (pk_fma) ----
    v2f cca = (v2f){0.f, 0.f}, ccb = (v2f){0.f, 0.f};
    v2f ccc = (v2f){0.f, 0.f}, ccd = (v2f){0.f, 0.f};
    #pragma unroll
    for (int k = 0; k < RPT; ++k) {
      v2f sp = e2[k][0] * R2[0];
      sp = __builtin_elementwise_fma(e2[k][1], R2[1], sp);
      sp = __builtin_elementwise_fma(e2[k][2], R2[2], sp);
      sp = __builtin_elementwise_fma(e2[k][3], R2[3], sp);
      float S  = fmaxf(sp.x + sp.y, 1e-37f);
      float w0 = a_i[k] * __builtin_amdgcn_rcpf(S);
      w0k[k] = w0;
      v2f wv = (v2f){w0, w0};
      cca = __builtin_elementwise_fma(e2[k][0], wv, cca);
      ccb = __builtin_elementwise_fma(e2[k][1], wv, ccb);
      ccc = __builtin_elementwise_fma(e2[k][2], wv, ccc);
      ccd = __builtin_elementwise_fma(e2[k][3], wv, ccd);
    }

    // ---- fold-and-halve reduction over lane bits 3,4,5 ----
    float s0 = dpp_add<0x128>(cca.x);
    float s1 = dpp_add<0x128>(cca.y);
    float s2 = dpp_add<0x128>(ccb.x);
    float s3 = dpp_add<0x128>(ccb.y);
    float s4 = dpp_add<0x128>(ccc.x);
    float s5 = dpp_add<0x128>(ccc.y);
    float s6 = dpp_add<0x128>(ccd.x);
    float s7 = dpp_add<0x128>(ccd.y);
    bool hb3 = (lane & 8) != 0;
    float k0 = hb3 ? s4 : s0;
    float k1 = hb3 ? s5 : s1;
    float k2 = hb3 ? s6 : s2;
    float k3 = hb3 ? s7 : s3;
    k0 += __shfl_xor(k0, 16);
    k1 += __shfl_xor(k1, 16);
    k2 += __shfl_xor(k2, 16);
    k3 += __shfl_xor(k3, 16);
    bool hb4 = (lane & 16) != 0;
    float u0 = hb4 ? k2 : k0;
    float u1 = hb4 ? k3 : k1;
    u0 += __shfl_xor(u0, 32);
    u1 += __shfl_xor(u1, 32);
    float val = ((lane & 32) != 0) ? u1 : u0;
    val = dpp_add<0xB1>(val);    // xor1
    val = dpp_add<0x4E>(val);    // xor2
    val = dpp_add<0x141>(val);   // xor4 (valid after xor1,xor2)

    if ((lane & 7) == 0) part2[widx] = val;
    __syncthreads();

    // ---- wave 0 alone finishes cross-wave sum and publishes R ----
    if (wave == 0) {
      const float4* pp = reinterpret_cast<const float4*>(&part2[col * 20]);
      float4 q0 = pp[0], q1 = pp[1], q2 = pp[2], q3 = pp[3];
      float acc = ((q0.x + q0.y) + (q0.z + q0.w)) + ((q1.x + q1.y) + (q1.z + q1.w))
                + ((q2.x + q2.y) + (q2.z + q2.w)) + ((q3.x + q3.y) + (q3.z + q3.w));
      acc = fmaxf(acc, 1e-35f);
      float rown = fminf(b_own * __builtin_amdgcn_rcpf(acc), CLAMP);
      if ((lane & 7) == 0) rbuf[col] = rown;
    }
    __syncthreads();

    // ---- all lanes fetch R via 2 broadcast b128 reads ----
    {
      const float4* rp = reinterpret_cast<const float4*>(&rbuf[0]);
      float4 q0 = rp[0], q1 = rp[1];
      R2[0] = (v2f){q0.x, q0.y};
      R2[1] = (v2f){q0.z, q0.w};
      R2[2] = (v2f){q1.x, q1.y};
      R2[3] = (v2f){q1.z, q1.w};
    }
  }

  // ---- epilogue: P = e * w0 * R, normalize by global total ----
  float lsum = 0.f;
  #pragma unroll
  for (int k = 0; k < RPT; ++k) {
    v2f wv = (v2f){w0k[k], w0k[k]};
    e2[k][0] = e2[k][0] * wv * R2[0];
    e2[k][1] = e2[k][1] * wv * R2[1];
    e2[k][2] = e2[k][2] * wv * R2[2];
    e2[k][3] = e2[k][3] * wv * R2[3];
    lsum += (e2[k][0].x + e2[k][0].y) + (e2[k][1].x + e2[k][1].y)
          + (e2[k][2].x + e2[k][2].y) + (e2[k][3].x + e2[k][3].y);
  }
  lsum = wsum(lsum);
  if (lane == 0) atomicAdd(&stot, lsum);
  __syncthreads();
  const float itot = __builtin_amdgcn_rcpf(stot);
  #pragma unroll
  for (int k = 0; k < RPT; ++k) {
    float4 o0 = make_float4(e2[k][0].x * itot, e2[k][0].y * itot,
                            e2[k][1].x * itot, e2[k][1].y * itot);
    float4 o1 = make_float4(e2[k][2].x * itot, e2[k][2].y * itot,
                            e2[k][3].x * itot, e2[k][3].y * itot);
    float4* op = reinterpret_cast<float4*>(out + (size_t)(tid + NT * k) * 8);
    op[0] = o0;
    op[1] = o1;
  }
}

extern "C" void kernel_launch(void* const* d_in, const int* in_sizes, int n_in,
                              void* d_out, int out_size, void* d_ws, size_t ws_size,
                              hipStream_t stream) {
  const float* theta    = (const float*)d_in[0];
  const float* phi      = (const float*)d_in[1];
  const float* sens_raw = (const float*)d_in[2];
  const float* n_raw    = (const float*)d_in[3];
  float* out = (float*)d_out;
  hipLaunchKernelGGL(sinkhorn_k, dim3(1), dim3(NT), 0, stream,
                     theta, phi, sens_raw, n_raw, out);
}